// Round 1
// baseline (1236.948 us; speedup 1.0000x reference)
//
#include <hip/hip_runtime.h>
#include <float.h>

#define VDIM 50257
#define NT   256
#define CAP  6144   // TRIG + max candidates per chunk (NT*4*4) -> exact, no drops
#define TRIG 2048

// monotone key: larger float <-> larger unsigned key (no NaNs in this data)
__device__ __forceinline__ unsigned f2key(float f){
  unsigned ix = __float_as_uint(f);
  return (ix & 0x80000000u) ? ~ix : (ix | 0x80000000u);
}
__device__ __forceinline__ float key2f(unsigned k){
  return (k & 0x80000000u) ? __uint_as_float(k & 0x7FFFFFFFu)
                           : __uint_as_float(~k);
}
__device__ __forceinline__ float gnoise(float uu){
  // -log(-log(u+eps)+eps)
  return -__logf(-__logf(uu + 1e-10f) + 1e-10f);
}

// exact k-th largest of cand[0..n) via 8-bit radix select; all 256 threads.
// digit scan parallelized on wave 0: per-lane 4-bin groups, shfl suffix scan,
// ballot locates the target group (replaces 256-iter serial tid0 loop).
__device__ float kth_largest(float* cand, int n, int k, int* hist,
                             int* s_dig, int* s_krem){
  unsigned prefix = 0u, maskb = 0u;
  int kr = k;
  const int tid = threadIdx.x;
  hist[tid] = 0;
  __syncthreads();
  for (int shift = 24; shift >= 0; shift -= 8){
    for (int i = tid; i < n; i += NT){
      unsigned key = f2key(cand[i]);
      if ((key & maskb) == prefix)
        atomicAdd(&hist[(key >> shift) & 0xFFu], 1);
    }
    __syncthreads();
    if (tid < 64){
      const int lane = tid;
      int h0 = hist[4*lane+0], h1 = hist[4*lane+1];
      int h2 = hist[4*lane+2], h3 = hist[4*lane+3];
      int gs = h0 + h1 + h2 + h3;
      int S = gs;                       // suffix-inclusive sum over groups
      #pragma unroll
      for (int off = 1; off < 64; off <<= 1){
        int o = __shfl_down(S, off);
        if (lane + off < 64) S += o;
      }
      unsigned long long bm = __ballot(S >= kr);
      int tstar = bm ? (63 - __clzll(bm)) : 0;
      if (lane == tstar){
        int c = S - gs;                 // count strictly above this group
        int d;
        for (d = 4*tstar + 3; d >= 4*tstar; --d){
          c += hist[d];
          if (c >= kr) break;
        }
        if (d < 4*tstar) d = 4*tstar;
        *s_dig  = d;
        *s_krem = kr - (c - hist[d]);
      }
    }
    __syncthreads();
    int d = *s_dig;
    kr = *s_krem; if (kr < 1) kr = 1;
    prefix |= ((unsigned)d) << shift;
    maskb  |= (0xFFu << shift);
    hist[tid] = 0;   // safe: wave0 finished reading hist before the barrier above
    __syncthreads();
  }
  return key2f(prefix);
}

// raise T0 to exact k-th largest of buffer, keep only elements >= it
__device__ void compact_buf(float* cand, int* hist, int* s_dig, int* s_krem,
                            int* s_cnt, float* s_T0, int kk){
  int n = *s_cnt; if (n > CAP) n = CAP;
  float tk = kth_largest(cand, n, kk, hist, s_dig, s_krem);
  float keep[24]; int m = 0;           // n<=6144 -> <=24 elements per thread
  for (int i = threadIdx.x; i < n; i += NT){
    float v = cand[i];
    if (v >= tk && m < 24) keep[m++] = v;
  }
  __syncthreads();
  if (threadIdx.x == 0){ *s_cnt = 0; *s_T0 = tk; }
  __syncthreads();
  for (int j = 0; j < m; ++j){
    int p = atomicAdd(s_cnt, 1);
    if (p < TRIG) cand[p] = keep[j];
  }
}

__global__ __launch_bounds__(NT)
void gumbel_topk_softmax(const float* __restrict__ logits,
                         const float* __restrict__ u,
                         const int* __restrict__ kptr,
                         float* __restrict__ out)
{
  __shared__ float cand[CAP];     // 24 KB candidate buffer (superset of row top-k)
  __shared__ int   hist[NT];      // radix histogram
  __shared__ float redf[8];
  __shared__ int   s_cnt, s_dig, s_krem;
  __shared__ float s_T0;

  const int tid  = threadIdx.x;
  const int lane = tid & 63;
  const size_t rbase = (size_t)blockIdx.x * VDIM;
  const float* lrow = logits + rbase;
  const float* urow = u + rbase;
  float* orow = out + rbase;

  // V is odd -> per-row float4 alignment peel
  const int head  = (int)((4 - (rbase & 3)) & 3);
  const int nv4   = (VDIM - head) >> 2;
  const int tailn = (VDIM - head) & 3;
  const int nedge = head + tailn;
  const float4* l4 = (const float4*)(lrow + head);
  const float4* u4 = (const float4*)(urow + head);
  float4* o4 = (float4*)(orow + head);

  int kk = *kptr;
  if (kk < 1) kk = 1;
  if (kk > TRIG) kk = TRIG;

  if (tid == 0){ s_cnt = 0; s_T0 = -FLT_MAX; }
  __syncthreads();

  float maxl = -FLT_MAX;

  // ---- Phase 1: scan, adaptive top-k candidate collection ----
  if (tid < nedge){
    int idx = (tid < head) ? tid : ((nv4 << 2) + tid);
    float l = lrow[idx];
    float g = l + gnoise(urow[idx]);
    maxl = fmaxf(maxl, l);
    int p = atomicAdd(&s_cnt, 1);
    if (p < CAP) cand[p] = g;
  }
  __syncthreads();

  for (int b = 0; b < nv4; b += NT * 4){
    const float t0 = s_T0;
    const int i0 = b + tid, i1 = i0 + NT, i2 = i0 + 2*NT, i3 = i0 + 3*NT;
    const bool h0 = i0 < nv4, h1 = i1 < nv4, h2 = i2 < nv4, h3 = i3 < nv4;
    float4 la, ua, lb, ub, lc, uc, ldd, ud;
    if (h0){ la  = l4[i0]; ua = u4[i0]; }
    if (h1){ lb  = l4[i1]; ub = u4[i1]; }
    if (h2){ lc  = l4[i2]; uc = u4[i2]; }
    if (h3){ ldd = l4[i3]; ud = u4[i3]; }

    // per-slot: compute gumbel logits, wave-aggregated candidate push
    #define PSLOT(hv, lv, uv) do { \
      float g0=0.f, g1=0.f, g2=0.f, g3=0.f; \
      bool c0=false, c1=false, c2=false, c3=false; \
      if (hv){ \
        g0 = lv.x + gnoise(uv.x); g1 = lv.y + gnoise(uv.y); \
        g2 = lv.z + gnoise(uv.z); g3 = lv.w + gnoise(uv.w); \
        maxl = fmaxf(maxl, fmaxf(fmaxf(lv.x, lv.y), fmaxf(lv.z, lv.w))); \
        c0 = g0 >= t0; c1 = g1 >= t0; c2 = g2 >= t0; c3 = g3 >= t0; \
      } \
      unsigned long long b0 = __ballot(c0), b1 = __ballot(c1); \
      unsigned long long b2 = __ballot(c2), b3 = __ballot(c3); \
      int n0 = __popcll(b0), n1 = __popcll(b1), n2 = __popcll(b2), n3 = __popcll(b3); \
      int tot = n0 + n1 + n2 + n3; \
      if (tot){ \
        int base = 0; \
        if (lane == 0) base = atomicAdd(&s_cnt, tot); \
        base = __shfl(base, 0); \
        unsigned long long lt = (1ull << lane) - 1ull; \
        int o0 = base + __popcll(b0 & lt); \
        int o1 = base + n0 + __popcll(b1 & lt); \
        int o2 = base + n0 + n1 + __popcll(b2 & lt); \
        int o3 = base + n0 + n1 + n2 + __popcll(b3 & lt); \
        if (c0 && o0 < CAP) cand[o0] = g0; \
        if (c1 && o1 < CAP) cand[o1] = g1; \
        if (c2 && o2 < CAP) cand[o2] = g2; \
        if (c3 && o3 < CAP) cand[o3] = g3; \
      } \
    } while(0)

    PSLOT(h0, la,  ua);
    PSLOT(h1, lb,  ub);
    PSLOT(h2, lc,  uc);
    PSLOT(h3, ldd, ud);
    #undef PSLOT

    __syncthreads();
    if (s_cnt > TRIG)
      compact_buf(cand, hist, &s_dig, &s_krem, &s_cnt, &s_T0, kk);
    __syncthreads();
  }

  // exact threshold = k-th largest of candidate buffer (== k-th largest of row)
  int n = s_cnt; if (n > CAP) n = CAP;
  float thr = kth_largest(cand, n, kk, hist, &s_dig, &s_krem);

  // block max of logits -> stability offset M
  #pragma unroll
  for (int off = 32; off > 0; off >>= 1)
    maxl = fmaxf(maxl, __shfl_down(maxl, off));
  if (lane == 0) redf[tid >> 6] = maxl;
  __syncthreads();
  float M = fmaxf(fmaxf(redf[0], redf[1]), fmaxf(redf[2], redf[3]));
  if (M < 0.f) M = 0.f;
  __syncthreads();

  // ---- Phase 2: numerator e = exp(l*sm - M) -> out, accumulate denominator ----
  float sl = 0.f;
  if (tid < nedge){
    int idx = (tid < head) ? tid : ((nv4 << 2) + tid);
    float l = lrow[idx];
    float g = l + gnoise(urow[idx]);
    float e = __expf(l * (1.f / (1.f + __expf(thr - g))) - M);
    orow[idx] = e;
    sl += e;
  }
  int i = tid;
  for (; i + NT < nv4; i += 2 * NT){
    float4 lva = l4[i],      uva = u4[i];
    float4 lvb = l4[i + NT], uvb = u4[i + NT];
    float4 ea, eb;
    ea.x = __expf(lva.x * (1.f / (1.f + __expf(thr - (lva.x + gnoise(uva.x))))) - M);
    ea.y = __expf(lva.y * (1.f / (1.f + __expf(thr - (lva.y + gnoise(uva.y))))) - M);
    ea.z = __expf(lva.z * (1.f / (1.f + __expf(thr - (lva.z + gnoise(uva.z))))) - M);
    ea.w = __expf(lva.w * (1.f / (1.f + __expf(thr - (lva.w + gnoise(uva.w))))) - M);
    eb.x = __expf(lvb.x * (1.f / (1.f + __expf(thr - (lvb.x + gnoise(uvb.x))))) - M);
    eb.y = __expf(lvb.y * (1.f / (1.f + __expf(thr - (lvb.y + gnoise(uvb.y))))) - M);
    eb.z = __expf(lvb.z * (1.f / (1.f + __expf(thr - (lvb.z + gnoise(uvb.z))))) - M);
    eb.w = __expf(lvb.w * (1.f / (1.f + __expf(thr - (lvb.w + gnoise(uvb.w))))) - M);
    o4[i]      = ea;
    o4[i + NT] = eb;
    sl += ((ea.x + ea.y) + (ea.z + ea.w)) + ((eb.x + eb.y) + (eb.z + eb.w));
  }
  for (; i < nv4; i += NT){
    float4 lv = l4[i], uv = u4[i];
    float4 ev;
    ev.x = __expf(lv.x * (1.f / (1.f + __expf(thr - (lv.x + gnoise(uv.x))))) - M);
    ev.y = __expf(lv.y * (1.f / (1.f + __expf(thr - (lv.y + gnoise(uv.y))))) - M);
    ev.z = __expf(lv.z * (1.f / (1.f + __expf(thr - (lv.z + gnoise(uv.z))))) - M);
    ev.w = __expf(lv.w * (1.f / (1.f + __expf(thr - (lv.w + gnoise(uv.w))))) - M);
    o4[i] = ev;
    sl += (ev.x + ev.y) + (ev.z + ev.w);
  }

  #pragma unroll
  for (int off = 32; off > 0; off >>= 1)
    sl += __shfl_down(sl, off);
  if (lane == 0) redf[4 + (tid >> 6)] = sl;
  __syncthreads();           // drains vmcnt(0): P2 stores complete before P3 reads
  float inv = 1.f / (redf[4] + redf[5] + redf[6] + redf[7]);

  // ---- Phase 3: pure streaming rescale of own numerators ----
  if (tid < nedge){
    int idx = (tid < head) ? tid : ((nv4 << 2) + tid);
    orow[idx] *= inv;
  }
  for (int j = tid; j < nv4; j += NT){
    float4 v = o4[j];
    v.x *= inv; v.y *= inv; v.z *= inv; v.w *= inv;
    o4[j] = v;
  }
}

extern "C" void kernel_launch(void* const* d_in, const int* in_sizes, int n_in,
                              void* d_out, int out_size, void* d_ws, size_t ws_size,
                              hipStream_t stream) {
  const float* logits = (const float*)d_in[0];
  const float* u      = (const float*)d_in[1];
  const int*   kptr   = (const int*)d_in[2];
  float* out = (float*)d_out;
  int B = in_sizes[0] / VDIM;   // 2048
  gumbel_topk_softmax<<<B, NT, 0, stream>>>(logits, u, kptr, out);
}